// Round 26
// baseline (432.476 us; speedup 1.0000x reference)
//
#include <hip/hip_runtime.h>
#include <cstddef>

// ---------------------------------------------------------------------------
// SimpleModuleNet. B=256, D=64, E=16, H=W=64, PROJ=512, FC=1024, NA=2.
//
// R2: 64->64 convs on matrix pipe (mfma_f32_16x16x32_f16, f16 hi/lo split).
// R4: proj MFMA + in-lane pool. R9/R17: all activations f16 hi/lo planes.
// R19: conv1 on matrix pipe. R25: fused weight transforms (427us best).
// R26: convm<16> oc-split across blockIdx.z (NT=2 ntiles/block, grid
//     (256,2,2) = 1024 blocks = 4 blocks/CU vs 2). Same mechanism as R7's
//     conv1 win: grid-limited occupancy. Staging replicated (L2-resident);
//     acc/B-frag footprint halves (~96 VGPR). convm<32> untouched (NT=4).
// ---------------------------------------------------------------------------

typedef _Float16 half8 __attribute__((ext_vector_type(8)));
typedef _Float16 half4_t __attribute__((ext_vector_type(4)));
typedef float f32x4 __attribute__((ext_vector_type(4)));

#define LO_SCALE 2048.0f
#define LO_INV (1.0f / 2048.0f)

// ---------------- fused weight transforms (R25): one dispatch.
__global__ __launch_bounds__(256)
void allwx_k(const float* __restrict__ stem_w0, const float* __restrict__ proj_w,
             const float* __restrict__ stem_w, const float* __restrict__ exp_w1,
             const float* __restrict__ exp_w2,
             _Float16* __restrict__ c1wF, _Float16* __restrict__ pwF,
             _Float16* __restrict__ stemtF, _Float16* __restrict__ e1tF,
             _Float16* __restrict__ e2tF) {
    int id = blockIdx.x * 256 + threadIdx.x;
    if (id < 2048) {
        int j = id & 7, l = (id >> 3) & 63, nt = id >> 9;
        int k = (l >> 4) * 8 + j, oc = nt * 16 + (l & 15);
        float v = 0.f;
        if (k < 27) {
            int ic = k / 9, tap = k % 9;
            v = stem_w0[(oc * 3 + ic) * 9 + tap];
        }
        _Float16 hi = (_Float16)v;
        c1wF[id] = hi;
        c1wF[2048 + id] = (_Float16)((v - (float)hi) * LO_SCALE);
        return;
    }
    id -= 2048;
    if (id < 32768) {
        int j = id & 7, l = (id >> 3) & 63, icc = (id >> 9) & 1, nt = id >> 10;
        int kl = (l >> 4) * 8 + j, ic = icc * 32 + kl, oc = nt * 16 + (l & 15);
        float v = proj_w[oc * 64 + ic];
        _Float16 hi = (_Float16)v;
        pwF[id] = hi;
        pwF[32768 + id] = (_Float16)((v - (float)hi) * LO_SCALE);
        return;
    }
    id -= 32768;
    const float* src;
    _Float16* dst;
    if (id < 110592) {
        src = stem_w; dst = stemtF;
    } else if (id < 110592 + 589824) {
        id -= 110592; src = exp_w1; dst = e1tF;
    } else {
        id -= 110592 + 589824; src = exp_w2; dst = e2tF;
    }
    int layer = id / 36864, idx = id % 36864;
    int j = idx & 7, l = (idx >> 3) & 63, nt = (idx >> 9) & 3;
    int icc = (idx >> 11) & 1, tap = idx >> 12;
    int kl = (l >> 4) * 8 + j, ic = icc * 32 + kl, oc = nt * 16 + (l & 15);
    float v = src[(size_t)layer * 36864 + (oc * 64 + ic) * 9 + tap];
    _Float16 hi = (_Float16)v;
    dst[(size_t)layer * 73728 + idx] = hi;
    dst[(size_t)layer * 73728 + 36864 + idx] = (_Float16)((v - (float)hi) * LO_SCALE);
}

// ---------------- conv1 (MFMA): 3->64, 64x64, pad1, +bias, relu, 2x2 pool.
__global__ __launch_bounds__(256, 2)
void conv1m_k(const float* __restrict__ img, const _Float16* __restrict__ wf,
              const float* __restrict__ b0, _Float16* __restrict__ out) {
    const size_t NE1 = 16777216;
    int b = blockIdx.x, t = blockIdx.y;        // t in [0,32)
    int ty0 = (t >> 2) * 8, tx0 = (t & 3) * 16;
    __shared__ float halo[3][10][18];
    __shared__ __align__(16) _Float16 lin[2 * 5120];  // [128 px][40] hi; lo +5120

    int tid = threadIdx.x, lane = tid & 63, wv = tid >> 6;
    const float* imb = img + (size_t)b * 3 * 64 * 64;
    for (int i = tid; i < 540; i += 256) {
        int c = i / 180, rem = i % 180, r = rem / 18, cc = rem % 18;
        int gy = ty0 - 1 + r, gx = tx0 - 1 + cc;
        float v = 0.f;
        if (gy >= 0 && gy < 64 && gx >= 0 && gx < 64) v = imb[(c * 64 + gy) * 64 + gx];
        halo[c][r][cc] = v;
    }
    __syncthreads();
    for (int i = tid; i < 512; i += 256) {
        int r = i >> 2, j8 = (i & 3) * 8;
        int MT = r >> 4, am = r & 15;
        int Q = MT * 4 + (am >> 2), s = am & 3;
        int py = (Q >> 3) * 2 + (s >> 1), px = (Q & 7) * 2 + (s & 1);
        half8 vh, vl;
#pragma unroll
        for (int j = 0; j < 8; ++j) {
            int k = j8 + j;
            float v = 0.f;
            if (k < 27) {
                int ic = k / 9, tap = k % 9;
                v = halo[ic][py + tap / 3][px + tap % 3];
            }
            _Float16 h = (_Float16)v;
            vh[j] = h;
            vl[j] = (_Float16)((v - (float)h) * LO_SCALE);
        }
        *(half8*)&lin[r * 40 + j8] = vh;
        *(half8*)&lin[5120 + r * 40 + j8] = vl;
    }
    __syncthreads();

    int am = lane & 15, k0 = (lane >> 4) * 8;
    float bv[4];
#pragma unroll
    for (int nt = 0; nt < 4; ++nt) bv[nt] = b0[nt * 16 + (lane & 15)];

    half8 bh[4], bl[4];
#pragma unroll
    for (int nt = 0; nt < 4; ++nt) {
        const _Float16* wp = wf + ((size_t)nt * 64 + lane) * 8;
        bh[nt] = *(const half8*)wp;
        bl[nt] = *(const half8*)(wp + 2048);
    }

    f32x4 acc1[2][4] = {};
    f32x4 acc2[2][4] = {};
#pragma unroll
    for (int mt = 0; mt < 2; ++mt) {
        int MT = wv * 2 + mt;
        const _Float16* ap = &lin[(MT * 16 + am) * 40 + k0];
        half8 ahi = *(const half8*)ap;
        half8 alo = *(const half8*)(ap + 5120);
#pragma unroll
        for (int nt = 0; nt < 4; ++nt) {
            acc1[mt][nt] = __builtin_amdgcn_mfma_f32_16x16x32_f16(
                ahi, bh[nt], acc1[mt][nt], 0, 0, 0);
            acc2[mt][nt] = __builtin_amdgcn_mfma_f32_16x16x32_f16(
                ahi, bl[nt], acc2[mt][nt], 0, 0, 0);
            acc2[mt][nt] = __builtin_amdgcn_mfma_f32_16x16x32_f16(
                alo, bh[nt], acc2[mt][nt], 0, 0, 0);
        }
    }

    int cn = lane & 15, rq = lane >> 4;
#pragma unroll
    for (int mt = 0; mt < 2; ++mt) {
        int MT = wv * 2 + mt;
        int Q = MT * 4 + rq;
        int qy = Q >> 3, qx = Q & 7;
#pragma unroll
        for (int nt = 0; nt < 4; ++nt) {
            int oc = nt * 16 + cn;
            float vals[4];
#pragma unroll
            for (int r = 0; r < 4; ++r)
                vals[r] = acc1[mt][nt][r] + acc2[mt][nt][r] * LO_INV + bv[nt];
            float m = fmaxf(fmaxf(vals[0], vals[1]), fmaxf(vals[2], vals[3]));
            m = fmaxf(m, 0.f);
            int opy = (ty0 >> 1) + qy, opx = (tx0 >> 1) + qx;
            size_t o = (((size_t)b * 32 + opy) * 32 + opx) * 64 + oc;
            _Float16 h = (_Float16)m;
            out[o] = h;
            out[NE1 + o] = (_Float16)((m - (float)h) * LO_SCALE);
        }
    }
}

// ---------------- MFMA conv 64->64 3x3 pad1; in/out/res = f16 hi/lo planes.
// Two-phase ic-chunk staging. NT = oc-ntiles per block (4 = all 64 oc;
// 2 = 32 oc, oc group selected by blockIdx.z) [R26].
template <int S, bool POOL, bool RES, int NT>
__global__ __launch_bounds__(256, 2)
void convm_k(const _Float16* __restrict__ in, _Float16* __restrict__ out,
             const _Float16* __restrict__ wf, const float* __restrict__ bias,
             const _Float16* __restrict__ res, const int* __restrict__ question,
             int qcol) {
    constexpr size_t NEin = (size_t)S * S * 64 * 256;
    constexpr size_t NEout = POOL ? NEin / 4 : NEin;
    int b = blockIdx.x, t = blockIdx.y;
    int ocg = blockIdx.z * NT;  // base ntile index
    constexpr int NTX = S / 16;
    int ty0 = (t / NTX) * 8, tx0 = (t % NTX) * 16;

    __shared__ __align__(16) _Float16 lds[2 * 7200];

    int tid = threadIdx.x, lane = tid & 63, wv = tid >> 6;
    const _Float16* wb = wf;
    const float* bb = bias;
    if (question) {
        int idx = question[b * 8 + qcol];
        wb += (size_t)idx * 73728;
        bb += idx * 64;
    }
    float bv[NT];
#pragma unroll
    for (int nt = 0; nt < NT; ++nt) bv[nt] = bb[(ocg + nt) * 16 + (lane & 15)];

    f32x4 acc1[2][NT] = {};
    f32x4 acc2[2][NT] = {};

    int am = lane & 15;
    int k0 = (lane >> 4) * 8;

    for (int icc = 0; icc < 2; ++icc) {
        __syncthreads();
        for (int i = tid; i < 720; i += 256) {
            int pix = i >> 2, j8 = (i & 3) * 8;
            int hy = pix / 18, hx = pix % 18;
            int gy = ty0 + hy - 1, gx = tx0 + hx - 1;
            half8 vh = {}, vl = {};
            if (gy >= 0 && gy < S && gx >= 0 && gx < S) {
                size_t src = (((size_t)b * S + gy) * S + gx) * 64 + icc * 32 + j8;
                vh = *(const half8*)&in[src];
                vl = *(const half8*)&in[NEin + src];
            }
            *(half8*)&lds[pix * 40 + j8] = vh;
            *(half8*)&lds[7200 + pix * 40 + j8] = vl;
        }
        __syncthreads();

#pragma unroll
        for (int ky = 0; ky < 3; ++ky)
#pragma unroll
            for (int kx = 0; kx < 3; ++kx) {
                int tap = ky * 3 + kx;
                const _Float16* wp = wb + (tap * 2 + icc) * 2048 + lane * 8;
                half8 bhi[NT], blo[NT];
#pragma unroll
                for (int nt = 0; nt < NT; ++nt) {
                    bhi[nt] = *(const half8*)(wp + (ocg + nt) * 512);
                    blo[nt] = *(const half8*)(wp + (ocg + nt) * 512 + 36864);
                }
#pragma unroll
                for (int mt = 0; mt < 2; ++mt) {
                    int MT = wv * 2 + mt;
                    int Q = MT * 4 + (am >> 2), s = am & 3;
                    int py = (Q >> 3) * 2 + (s >> 1), px = (Q & 7) * 2 + (s & 1);
                    const _Float16* ap = &lds[((py + ky) * 18 + (px + kx)) * 40 + k0];
                    half8 ahi = *(const half8*)ap;
                    half8 alo = *(const half8*)(ap + 7200);
#pragma unroll
                    for (int nt = 0; nt < NT; ++nt) {
                        acc1[mt][nt] = __builtin_amdgcn_mfma_f32_16x16x32_f16(
                            ahi, bhi[nt], acc1[mt][nt], 0, 0, 0);
                        acc2[mt][nt] = __builtin_amdgcn_mfma_f32_16x16x32_f16(
                            ahi, blo[nt], acc2[mt][nt], 0, 0, 0);
                        acc2[mt][nt] = __builtin_amdgcn_mfma_f32_16x16x32_f16(
                            alo, bhi[nt], acc2[mt][nt], 0, 0, 0);
                    }
                }
            }
    }

    int cn = lane & 15, rq = lane >> 4;
#pragma unroll
    for (int mt = 0; mt < 2; ++mt) {
        int MT = wv * 2 + mt;
        int Q = MT * 4 + rq;
        int qy = Q >> 3, qx = Q & 7;
#pragma unroll
        for (int nt = 0; nt < NT; ++nt) {
            int oc = (ocg + nt) * 16 + cn;
            float vals[4];
#pragma unroll
            for (int r = 0; r < 4; ++r)
                vals[r] = acc1[mt][nt][r] + acc2[mt][nt][r] * LO_INV + bv[nt];
            if (POOL) {
                float m = fmaxf(fmaxf(vals[0], vals[1]), fmaxf(vals[2], vals[3]));
                m = fmaxf(m, 0.f);
                int opy = (ty0 >> 1) + qy, opx = (tx0 >> 1) + qx;
                size_t o = (((size_t)b * (S / 2) + opy) * (S / 2) + opx) * 64 + oc;
                _Float16 h = (_Float16)m;
                out[o] = h;
                out[NEout + o] = (_Float16)((m - (float)h) * LO_SCALE);
            } else {
#pragma unroll
                for (int r = 0; r < 4; ++r) {
                    int py = qy * 2 + (r >> 1), px = qx * 2 + (r & 1);
                    size_t o = (((size_t)b * S + (ty0 + py)) * S + (tx0 + px)) * 64 + oc;
                    float v = vals[r];
                    if (RES) v += (float)res[o] + (float)res[NEin + o] * LO_INV;
                    v = fmaxf(v, 0.f);
                    _Float16 h = (_Float16)v;
                    out[o] = h;
                    out[NEout + o] = (_Float16)((v - (float)h) * LO_SCALE);
                }
            }
        }
    }
}

// ---------------- proj (MFMA): per-sample GEMM C[256px][512oc], K=64.
__global__ __launch_bounds__(256)
void projm_k(const _Float16* __restrict__ in /* planes, NE2=4194304 */,
             const _Float16* __restrict__ pw, const float* __restrict__ bias,
             _Float16* __restrict__ outh /* hi plane; lo at +8388608 */) {
    const size_t NE2 = 4194304;
    int b = blockIdx.x;
    __shared__ float lt[64 * 65];
    int tid = threadIdx.x, lane = tid & 63, wv = tid >> 6;
    int row = lane & 15, cseg = lane >> 4;

    half8 ah[4][2], al[4][2];
#pragma unroll
    for (int mt = 0; mt < 4; ++mt) {
        int MT = wv * 4 + mt;
        int Q = MT * 4 + (row >> 2), s = row & 3;
        int y = (Q >> 3) * 2 + (s >> 1), x = (Q & 7) * 2 + (s & 1);
        size_t pb = ((size_t)b * 256 + y * 16 + x) * 64 + cseg * 8;
#pragma unroll
        for (int icc = 0; icc < 2; ++icc) {
            ah[mt][icc] = *(const half8*)&in[pb + icc * 32];
            al[mt][icc] = *(const half8*)&in[NE2 + pb + icc * 32];
        }
    }

    for (int ogl = 0; ogl < 4; ++ogl) {
        int og = blockIdx.y * 4 + ogl;
        half8 bh[4][2], bl[4][2];
#pragma unroll
        for (int ntl = 0; ntl < 4; ++ntl)
#pragma unroll
            for (int icc = 0; icc < 2; ++icc) {
                int nt = og * 4 + ntl;
                const _Float16* wp = pw + ((nt * 2 + icc) * 64 + lane) * 8;
                bh[ntl][icc] = *(const half8*)wp;
                bl[ntl][icc] = *(const half8*)(wp + 32768);
            }
        f32x4 a1[4][4] = {};
        f32x4 a2[4][4] = {};
#pragma unroll
        for (int icc = 0; icc < 2; ++icc)
#pragma unroll
            for (int mt = 0; mt < 4; ++mt)
#pragma unroll
                for (int ntl = 0; ntl < 4; ++ntl) {
                    a1[mt][ntl] = __builtin_amdgcn_mfma_f32_16x16x32_f16(
                        ah[mt][icc], bh[ntl][icc], a1[mt][ntl], 0, 0, 0);
                    a2[mt][ntl] = __builtin_amdgcn_mfma_f32_16x16x32_f16(
                        ah[mt][icc], bl[ntl][icc], a2[mt][ntl], 0, 0, 0);
                    a2[mt][ntl] = __builtin_amdgcn_mfma_f32_16x16x32_f16(
                        al[mt][icc], bh[ntl][icc], a2[mt][ntl], 0, 0, 0);
                }
        if (ogl) __syncthreads();
#pragma unroll
        for (int mt = 0; mt < 4; ++mt) {
            int Qg = (wv * 4 + mt) * 4 + (lane >> 4);
#pragma unroll
            for (int ntl = 0; ntl < 4; ++ntl) {
                float bvv = bias[og * 64 + ntl * 16 + (lane & 15)];
                float v0 = a1[mt][ntl][0] + a2[mt][ntl][0] * LO_INV + bvv;
                float v1 = a1[mt][ntl][1] + a2[mt][ntl][1] * LO_INV + bvv;
                float v2 = a1[mt][ntl][2] + a2[mt][ntl][2] * LO_INV + bvv;
                float v3 = a1[mt][ntl][3] + a2[mt][ntl][3] * LO_INV + bvv;
                float m = fmaxf(fmaxf(fmaxf(v0, v1), fmaxf(v2, v3)), 0.f);
                lt[(ntl * 16 + (lane & 15)) * 65 + Qg] = m;
            }
        }
        __syncthreads();
#pragma unroll
        for (int r = 0; r < 16; ++r) {
            int f = r * 256 + tid;
            int ol = f >> 6, q = f & 63;
            float v = lt[ol * 65 + q];
            _Float16 h = (_Float16)v;
            _Float16 l = (_Float16)((v - (float)h) * LO_SCALE);
            size_t o = (size_t)b * 32768 + og * 4096 + ol * 64 + q;
            outh[o] = h;
            outh[8388608 + o] = l;
        }
    }
}

// ---------------- fc1 MFMA GEMM: C[256][1024] = A[256][32768] @ W[1024][32768]^T
// R19 form: double-buffered LDS stride 40, one barrier per K-step.
__global__ __launch_bounds__(256)
void fc1m_k(const _Float16* __restrict__ Ahl /* hi; lo at +8388608 */,
            const float* __restrict__ W,
            float* __restrict__ partial /* [32][256][1024] */) {
    int bid = blockIdx.x;
    int lid = (bid & 7) * 64 + (bid >> 3);   // bijective, 512 = 8*64
    int mt = lid & 1, nt = (lid >> 1) & 7, ks = lid >> 4;  // ks 0..31
    int m0 = mt * 128, n0 = nt * 128;
    const _Float16* Ab = Ahl + (size_t)m0 * 32768 + ks * 1024;
    const float* Wb = W + (size_t)n0 * 32768 + ks * 1024;

    __shared__ __align__(16) _Float16 lds[40960];  // 2 buffers x 20480

    int tid = threadIdx.x, lane = tid & 63, wv = tid >> 6;
    int wm = (wv & 1) * 64, wn = (wv >> 1) * 64;
    int koff = (lane >> 4) * 8, fr = lane & 15;

    f32x4 acc1[4][4] = {};
    f32x4 acc2[4][4] = {};

    int arow[2], ak8[2];
#pragma unroll
    for (int p = 0; p < 2; ++p) {
        int idx = p * 256 + tid;
        arow[p] = idx >> 2;
        ak8[p] = (idx & 3) * 8;
    }
    int wrow[4], wc4[4];
#pragma unroll
    for (int p = 0; p < 4; ++p) {
        int idx = p * 256 + tid;
        wrow[p] = idx >> 3;
        wc4[p] = (idx & 7) << 2;
    }

    half8 pa_h[2], pa_l[2];
    float4 rw[4];

#pragma unroll
    for (int p = 0; p < 2; ++p) {
        pa_h[p] = *(const half8*)&Ab[(size_t)arow[p] * 32768 + ak8[p]];
        pa_l[p] = *(const half8*)&Ab[8388608 + (size_t)arow[p] * 32768 + ak8[p]];
    }
#pragma unroll
    for (int p = 0; p < 4; ++p)
        rw[p] = *(const float4*)&Wb[(size_t)wrow[p] * 32768 + wc4[p]];
    {
        _Float16* b0p = lds;
#pragma unroll
        for (int p = 0; p < 2; ++p) {
            *(half8*)&b0p[arow[p] * 40 + ak8[p]] = pa_h[p];
            *(half8*)&b0p[5120 + arow[p] * 40 + ak8[p]] = pa_l[p];
        }
#pragma unroll
        for (int p = 0; p < 4; ++p) {
            float4 u = rw[p];
            _Float16 g0 = (_Float16)u.x, g1 = (_Float16)u.y;
            _Float16 g2 = (_Float16)u.z, g3 = (_Float16)u.w;
            half4_t gh = {g0, g1, g2, g3};
            half4_t gl = {(_Float16)((u.x - (float)g0) * LO_SCALE),
                          (_Float16)((u.y - (float)g1) * LO_SCALE),
                          (_Float16)((u.z - (float)g2) * LO_SCALE),
                          (_Float16)((u.w - (float)g3) * LO_SCALE)};
            *(half4_t*)&b0p[10240 + wrow[p] * 40 + wc4[p]] = gh;
            *(half4_t*)&b0p[15360 + wrow[p] * 40 + wc4[p]] = gl;
        }
    }
#pragma unroll
    for (int p = 0; p < 2; ++p) {
        pa_h[p] = *(const half8*)&Ab[(size_t)arow[p] * 32768 + 32 + ak8[p]];
        pa_l[p] = *(const half8*)&Ab[8388608 + (size_t)arow[p] * 32768 + 32 + ak8[p]];
    }
#pragma unroll
    for (int p = 0; p < 4; ++p)
        rw[p] = *(const float4*)&Wb[(size_t)wrow[p] * 32768 + 32 + wc4[p]];
    __syncthreads();

    for (int kt = 0; kt < 32; ++kt) {
        _Float16* cur = lds + (kt & 1) * 20480;
        _Float16* nxt = lds + ((kt + 1) & 1) * 20480;
        if (kt < 31) {
#pragma unroll
            for (int p = 0; p < 2; ++p) {
                *(half8*)&nxt[arow[p] * 40 + ak8[p]] = pa_h[p];
                *(half8*)&nxt[5120 + arow[p] * 40 + ak8[p]] = pa_l[p];
            }
#pragma unroll
            for (int p = 0; p < 4; ++p) {
                float4 u = rw[p];
                _Float16 g0 = (_Float16)u.x, g1 = (_Float16)u.y;
                _Float16 g2 = (_Float16)u.z, g3 = (_Float16)u.w;
                half4_t gh = {g0, g1, g2, g3};
                half4_t gl = {(_Float16)((u.x - (float)g0) * LO_SCALE),
                              (_Float16)((u.y - (float)g1) * LO_SCALE),
                              (_Float16)((u.z - (float)g2) * LO_SCALE),
                              (_Float16)((u.w - (float)g3) * LO_SCALE)};
                *(half4_t*)&nxt[10240 + wrow[p] * 40 + wc4[p]] = gh;
                *(half4_t*)&nxt[15360 + wrow[p] * 40 + wc4[p]] = gl;
            }
            if (kt < 30) {
                int kb = (kt + 2) * 32;
#pragma unroll
                for (int p = 0; p < 2; ++p) {
                    pa_h[p] = *(const half8*)&Ab[(size_t)arow[p] * 32768 + kb + ak8[p]];
                    pa_l[p] = *(const half8*)&Ab[8388608 + (size_t)arow[p] * 32768 + kb + ak8[p]];
                }
#pragma unroll
                for (int p = 0; p < 4; ++p)
                    rw[p] = *(const float4*)&Wb[(size_t)wrow[p] * 32768 + kb + wc4[p]];
            }
        }
        half8 bh[4], bl[4];
#pragma unroll
        for (int nf = 0; nf < 4; ++nf) {
            int r = wn + nf * 16 + fr;
            bh[nf] = *(const half8*)&cur[10240 + r * 40 + koff];
            bl[nf] = *(const half8*)&cur[15360 + r * 40 + koff];
        }
#pragma unroll
        for (int mf = 0; mf < 4; ++mf) {
            int r = wm + mf * 16 + fr;
            half8 ah = *(const half8*)&cur[r * 40 + koff];
            half8 al = *(const half8*)&cur[5120 + r * 40 + koff];
#pragma unroll
            for (int nf = 0; nf < 4; ++nf) {
                acc1[mf][nf] = __builtin_amdgcn_mfma_f32_16x16x32_f16(
                    ah, bh[nf], acc1[mf][nf], 0, 0, 0);
                acc2[mf][nf] = __builtin_amdgcn_mfma_f32_16x16x32_f16(
                    ah, bl[nf], acc2[mf][nf], 0, 0, 0);
                acc2[mf][nf] = __builtin_amdgcn_mfma_f32_16x16x32_f16(
                    al, bh[nf], acc2[mf][nf], 0, 0, 0);
            }
        }
        __syncthreads();
    }

    int rq = lane >> 4, cn = lane & 15;
    float* pb = partial + (size_t)ks * 262144;
#pragma unroll
    for (int mf = 0; mf < 4; ++mf)
#pragma unroll
        for (int nf = 0; nf < 4; ++nf) {
            int n = n0 + wn + nf * 16 + cn;
#pragma unroll
            for (int r = 0; r < 4; ++r) {
                int m = m0 + wm + mf * 16 + rq * 4 + r;
                pb[(size_t)m * 1024 + n] = acc1[mf][nf][r] + acc2[mf][nf][r] * LO_INV;
            }
        }
}

__global__ __launch_bounds__(256)
void fc1red_k(const float* __restrict__ partial, const float* __restrict__ b1,
              float* __restrict__ fc1o_t /* [n][m] */) {
    int m = blockIdx.x;
    int n0 = threadIdx.x * 4;
    float4 s = {0.f, 0.f, 0.f, 0.f};
    for (int ks = 0; ks < 32; ++ks) {
        float4 v = *(const float4*)&partial[((size_t)ks * 256 + m) * 1024 + n0];
        s.x += v.x; s.y += v.y; s.z += v.z; s.w += v.w;
    }
    fc1o_t[(size_t)(n0 + 0) * 256 + m] = fmaxf(s.x + b1[n0 + 0], 0.f);
    fc1o_t[(size_t)(n0 + 1) * 256 + m] = fmaxf(s.y + b1[n0 + 1], 0.f);
    fc1o_t[(size_t)(n0 + 2) * 256 + m] = fmaxf(s.z + b1[n0 + 2], 0.f);
    fc1o_t[(size_t)(n0 + 3) * 256 + m] = fmaxf(s.w + b1[n0 + 3], 0.f);
}

__global__ __launch_bounds__(256)
void fc2a_k(const float* __restrict__ a_t, const float* __restrict__ W2,
            float* __restrict__ p2) {
    int n2 = blockIdx.x, ks = blockIdx.y;
    int m = threadIdx.x;
    float acc = 0.f;
    for (int k = ks * 256; k < ks * 256 + 256; ++k)
        acc = fmaf(a_t[(size_t)k * 256 + m], W2[n2 * 1024 + k], acc);
    p2[((size_t)n2 * 4 + ks) * 256 + m] = acc;
}

__global__ __launch_bounds__(512)
void fc2b_k(const float* __restrict__ p2, const float* __restrict__ b2,
            float* __restrict__ out) {
    int i = threadIdx.x;
    int m = i >> 1, n2 = i & 1;
    float s = b2[n2];
#pragma unroll
    for (int ks = 0; ks < 4; ++ks) s += p2[((size_t)n2 * 4 + ks) * 256 + m];
    out[m * 2 + n2] = s;
}

// ---------------------------------------------------------------------------
extern "C" void kernel_launch(void* const* d_in, const int* in_sizes, int n_in,
                              void* d_out, int out_size, void* d_ws, size_t ws_size,
                              hipStream_t stream) {
    const float* image   = (const float*)d_in[0];
    const int*   question= (const int*)d_in[1];
    const float* stem_w0 = (const float*)d_in[2];
    const float* stem_b0 = (const float*)d_in[3];
    const float* stem_w  = (const float*)d_in[4];
    const float* stem_b  = (const float*)d_in[5];
    const float* exp_w1  = (const float*)d_in[6];
    const float* exp_b1  = (const float*)d_in[7];
    const float* exp_w2  = (const float*)d_in[8];
    const float* exp_b2  = (const float*)d_in[9];
    const float* proj_w  = (const float*)d_in[10];
    const float* proj_b  = (const float*)d_in[11];
    const float* fc1_w   = (const float*)d_in[12];
    const float* fc1_b   = (const float*)d_in[13];
    const float* fc2_w   = (const float*)d_in[14];
    const float* fc2_b   = (const float*)d_in[15];
    (void)in_sizes; (void)n_in; (void)out_size; (void)ws_size;

    float* ws = (float*)d_ws;
    const size_t A = 16777216, P2N = 4194304;
    float* wtr   = ws + 2 * A + P2N;
    _Float16* c1wF = (_Float16*)wtr;            // 4096 f16 = 2048 floats
    _Float16* pwF = (_Float16*)(wtr + 2048);    // 65536 f16 = 32768 floats
    float* pfc2  = wtr + 2048 + 32768;          // 2048 fp32
    _Float16* f16b = (_Float16*)(wtr + 36864);
    _Float16* stemtF = f16b;                    // 3 layers * 73728 f16
    _Float16* e1tF   = f16b + 3 * 73728;        // 16 layers
    _Float16* e2tF   = e1tF + 16 * 73728;       // 16 layers
    _Float16* p1h  = (_Float16*)ws;
    _Float16* h2h  = (_Float16*)(ws + A);
    _Float16* p2h  = (_Float16*)(ws + 2 * A);
    _Float16* hAh  = (_Float16*)ws;             // p1 dead by then
    _Float16* hBh  = (_Float16*)(ws + P2N);
    _Float16* hCh  = (_Float16*)(ws + 2 * P2N);
    _Float16* pool3h = (_Float16*)(ws + A);     // h2 dead by then
    float* fc1o  = ws + A + 8388608;
    float* fc1p  = ws;                          // [32][256][1024]

    // fused weight transforms (1325056 ids = 5176 blocks)
    allwx_k<<<5176, 256, 0, stream>>>(stem_w0, proj_w, stem_w, exp_w1, exp_w2,
                                      c1wF, pwF, stemtF, e1tF, e2tF);

    // stem
    conv1m_k<<<dim3(256, 32), 256, 0, stream>>>(image, c1wF, stem_b0, p1h);
    convm_k<32, false, false, 4><<<dim3(256, 8, 1), 256, 0, stream>>>(
        p1h, h2h, stemtF, stem_b, nullptr, nullptr, 0);
    convm_k<32, true, false, 4><<<dim3(256, 8, 1), 256, 0, stream>>>(
        h2h, p2h, stemtF + 73728, stem_b + 64, nullptr, nullptr, 0);
    convm_k<16, false, false, 2><<<dim3(256, 2, 2), 256, 0, stream>>>(
        p2h, hAh, stemtF + 2 * 73728, stem_b + 128, nullptr, nullptr, 0);

    // expert residual rounds (cols 4,5,7)
    const int cols[3] = {4, 5, 7};
    _Float16* hin = hAh;
    _Float16* hmid = hBh;
    _Float16* hout = hCh;
    for (int r = 0; r < 3; ++r) {
        convm_k<16, false, false, 2><<<dim3(256, 2, 2), 256, 0, stream>>>(
            hin, hmid, e1tF, exp_b1, nullptr, question, cols[r]);
        convm_k<16, false, true, 2><<<dim3(256, 2, 2), 256, 0, stream>>>(
            hmid, hout, e2tF, exp_b2, hin, question, cols[r]);
        _Float16* tp = hin; hin = hout; hout = hmid; hmid = tp;
    }
    // hin == final h (ws+0)

    // head
    projm_k<<<dim3(256, 2), 256, 0, stream>>>(hin, pwF, proj_b, pool3h);
    fc1m_k<<<512, 256, 0, stream>>>(pool3h, fc1_w, fc1p);
    fc1red_k<<<256, 256, 0, stream>>>(fc1p, fc1_b, fc1o);
    fc2a_k<<<dim3(2, 4), 256, 0, stream>>>(fc1o, fc2_w, pfc2);
    fc2b_k<<<1, 512, 0, stream>>>(pfc2, fc2_b, (float*)d_out);
}

// Round 27
// 427.010 us; speedup vs baseline: 1.0128x; 1.0128x over previous
//
#include <hip/hip_runtime.h>
#include <cstddef>

// ---------------------------------------------------------------------------
// SimpleModuleNet. B=256, D=64, E=16, H=W=64, PROJ=512, FC=1024, NA=2.
// FINAL (R27 = R25 config, measured best 427us):
//   - All convs + proj + fc1 on the matrix pipe (mfma_f32_16x16x32_f16,
//     f16 hi/lo split, lo plane scaled 2048 -> ~2^-22 rounding error).
//   - All inter-layer activations stored as f16 hi/lo planes (staging and
//     fragment loads are pure half8 copies, zero conversion VALU).
//   - conv1 as implicit GEMM (K=27 pad 32); convm 8x16-px tile, quad-major M
//     -> in-lane 2x2 pool; two-phase ic staging; fused bias/relu/res/pool.
//   - fc1: 128x128 tile, split-K 32, dbuf LDS stride-40, reg prefetch.
//   - Single fused weight-transform dispatch.
// Trajectory: 2427 (R1 naive) -> 1417 (fc1 reg-GEMM) -> 668 (MFMA convs) ->
//   514 (fc1 MFMA) -> 435 (conv1 MFMA) -> 427 (fused transforms).
// Failed-experiment ledger (all reverted): dbuf-neutral, split-K-64, direct-
//   global-A, stride-42 (alignment!), merged-stage, asm-pin, tap-major,
//   depth-2 prefetch (VGPR), convm oc-split.
// ---------------------------------------------------------------------------

typedef _Float16 half8 __attribute__((ext_vector_type(8)));
typedef _Float16 half4_t __attribute__((ext_vector_type(4)));
typedef float f32x4 __attribute__((ext_vector_type(4)));

#define LO_SCALE 2048.0f
#define LO_INV (1.0f / 2048.0f)

// ---------------- fused weight transforms: one dispatch.
__global__ __launch_bounds__(256)
void allwx_k(const float* __restrict__ stem_w0, const float* __restrict__ proj_w,
             const float* __restrict__ stem_w, const float* __restrict__ exp_w1,
             const float* __restrict__ exp_w2,
             _Float16* __restrict__ c1wF, _Float16* __restrict__ pwF,
             _Float16* __restrict__ stemtF, _Float16* __restrict__ e1tF,
             _Float16* __restrict__ e2tF) {
    int id = blockIdx.x * 256 + threadIdx.x;
    if (id < 2048) {
        int j = id & 7, l = (id >> 3) & 63, nt = id >> 9;
        int k = (l >> 4) * 8 + j, oc = nt * 16 + (l & 15);
        float v = 0.f;
        if (k < 27) {
            int ic = k / 9, tap = k % 9;
            v = stem_w0[(oc * 3 + ic) * 9 + tap];
        }
        _Float16 hi = (_Float16)v;
        c1wF[id] = hi;
        c1wF[2048 + id] = (_Float16)((v - (float)hi) * LO_SCALE);
        return;
    }
    id -= 2048;
    if (id < 32768) {
        int j = id & 7, l = (id >> 3) & 63, icc = (id >> 9) & 1, nt = id >> 10;
        int kl = (l >> 4) * 8 + j, ic = icc * 32 + kl, oc = nt * 16 + (l & 15);
        float v = proj_w[oc * 64 + ic];
        _Float16 hi = (_Float16)v;
        pwF[id] = hi;
        pwF[32768 + id] = (_Float16)((v - (float)hi) * LO_SCALE);
        return;
    }
    id -= 32768;
    const float* src;
    _Float16* dst;
    if (id < 110592) {
        src = stem_w; dst = stemtF;
    } else if (id < 110592 + 589824) {
        id -= 110592; src = exp_w1; dst = e1tF;
    } else {
        id -= 110592 + 589824; src = exp_w2; dst = e2tF;
    }
    int layer = id / 36864, idx = id % 36864;
    int j = idx & 7, l = (idx >> 3) & 63, nt = (idx >> 9) & 3;
    int icc = (idx >> 11) & 1, tap = idx >> 12;
    int kl = (l >> 4) * 8 + j, ic = icc * 32 + kl, oc = nt * 16 + (l & 15);
    float v = src[(size_t)layer * 36864 + (oc * 64 + ic) * 9 + tap];
    _Float16 hi = (_Float16)v;
    dst[(size_t)layer * 73728 + idx] = hi;
    dst[(size_t)layer * 73728 + 36864 + idx] = (_Float16)((v - (float)hi) * LO_SCALE);
}

// ---------------- conv1 (MFMA): 3->64, 64x64, pad1, +bias, relu, 2x2 pool.
__global__ __launch_bounds__(256, 2)
void conv1m_k(const float* __restrict__ img, const _Float16* __restrict__ wf,
              const float* __restrict__ b0, _Float16* __restrict__ out) {
    const size_t NE1 = 16777216;
    int b = blockIdx.x, t = blockIdx.y;        // t in [0,32)
    int ty0 = (t >> 2) * 8, tx0 = (t & 3) * 16;
    __shared__ float halo[3][10][18];
    __shared__ __align__(16) _Float16 lin[2 * 5120];  // [128 px][40] hi; lo +5120

    int tid = threadIdx.x, lane = tid & 63, wv = tid >> 6;
    const float* imb = img + (size_t)b * 3 * 64 * 64;
    for (int i = tid; i < 540; i += 256) {
        int c = i / 180, rem = i % 180, r = rem / 18, cc = rem % 18;
        int gy = ty0 - 1 + r, gx = tx0 - 1 + cc;
        float v = 0.f;
        if (gy >= 0 && gy < 64 && gx >= 0 && gx < 64) v = imb[(c * 64 + gy) * 64 + gx];
        halo[c][r][cc] = v;
    }
    __syncthreads();
    for (int i = tid; i < 512; i += 256) {
        int r = i >> 2, j8 = (i & 3) * 8;
        int MT = r >> 4, am = r & 15;
        int Q = MT * 4 + (am >> 2), s = am & 3;
        int py = (Q >> 3) * 2 + (s >> 1), px = (Q & 7) * 2 + (s & 1);
        half8 vh, vl;
#pragma unroll
        for (int j = 0; j < 8; ++j) {
            int k = j8 + j;
            float v = 0.f;
            if (k < 27) {
                int ic = k / 9, tap = k % 9;
                v = halo[ic][py + tap / 3][px + tap % 3];
            }
            _Float16 h = (_Float16)v;
            vh[j] = h;
            vl[j] = (_Float16)((v - (float)h) * LO_SCALE);
        }
        *(half8*)&lin[r * 40 + j8] = vh;
        *(half8*)&lin[5120 + r * 40 + j8] = vl;
    }
    __syncthreads();

    int am = lane & 15, k0 = (lane >> 4) * 8;
    float bv[4];
#pragma unroll
    for (int nt = 0; nt < 4; ++nt) bv[nt] = b0[nt * 16 + (lane & 15)];

    half8 bh[4], bl[4];
#pragma unroll
    for (int nt = 0; nt < 4; ++nt) {
        const _Float16* wp = wf + ((size_t)nt * 64 + lane) * 8;
        bh[nt] = *(const half8*)wp;
        bl[nt] = *(const half8*)(wp + 2048);
    }

    f32x4 acc1[2][4] = {};
    f32x4 acc2[2][4] = {};
#pragma unroll
    for (int mt = 0; mt < 2; ++mt) {
        int MT = wv * 2 + mt;
        const _Float16* ap = &lin[(MT * 16 + am) * 40 + k0];
        half8 ahi = *(const half8*)ap;
        half8 alo = *(const half8*)(ap + 5120);
#pragma unroll
        for (int nt = 0; nt < 4; ++nt) {
            acc1[mt][nt] = __builtin_amdgcn_mfma_f32_16x16x32_f16(
                ahi, bh[nt], acc1[mt][nt], 0, 0, 0);
            acc2[mt][nt] = __builtin_amdgcn_mfma_f32_16x16x32_f16(
                ahi, bl[nt], acc2[mt][nt], 0, 0, 0);
            acc2[mt][nt] = __builtin_amdgcn_mfma_f32_16x16x32_f16(
                alo, bh[nt], acc2[mt][nt], 0, 0, 0);
        }
    }

    int cn = lane & 15, rq = lane >> 4;
#pragma unroll
    for (int mt = 0; mt < 2; ++mt) {
        int MT = wv * 2 + mt;
        int Q = MT * 4 + rq;
        int qy = Q >> 3, qx = Q & 7;
#pragma unroll
        for (int nt = 0; nt < 4; ++nt) {
            int oc = nt * 16 + cn;
            float vals[4];
#pragma unroll
            for (int r = 0; r < 4; ++r)
                vals[r] = acc1[mt][nt][r] + acc2[mt][nt][r] * LO_INV + bv[nt];
            float m = fmaxf(fmaxf(vals[0], vals[1]), fmaxf(vals[2], vals[3]));
            m = fmaxf(m, 0.f);
            int opy = (ty0 >> 1) + qy, opx = (tx0 >> 1) + qx;
            size_t o = (((size_t)b * 32 + opy) * 32 + opx) * 64 + oc;
            _Float16 h = (_Float16)m;
            out[o] = h;
            out[NE1 + o] = (_Float16)((m - (float)h) * LO_SCALE);
        }
    }
}

// ---------------- MFMA conv 64->64 3x3 pad1; in/out/res = f16 hi/lo planes.
// Two-phase ic-chunk staging.
template <int S, bool POOL, bool RES>
__global__ __launch_bounds__(256, 2)
void convm_k(const _Float16* __restrict__ in, _Float16* __restrict__ out,
             const _Float16* __restrict__ wf, const float* __restrict__ bias,
             const _Float16* __restrict__ res, const int* __restrict__ question,
             int qcol) {
    constexpr size_t NEin = (size_t)S * S * 64 * 256;
    constexpr size_t NEout = POOL ? NEin / 4 : NEin;
    int b = blockIdx.x, t = blockIdx.y;
    constexpr int NTX = S / 16;
    int ty0 = (t / NTX) * 8, tx0 = (t % NTX) * 16;

    __shared__ __align__(16) _Float16 lds[2 * 7200];

    int tid = threadIdx.x, lane = tid & 63, wv = tid >> 6;
    const _Float16* wb = wf;
    const float* bb = bias;
    if (question) {
        int idx = question[b * 8 + qcol];
        wb += (size_t)idx * 73728;
        bb += idx * 64;
    }
    float bv[4];
#pragma unroll
    for (int nt = 0; nt < 4; ++nt) bv[nt] = bb[nt * 16 + (lane & 15)];

    f32x4 acc1[2][4] = {};
    f32x4 acc2[2][4] = {};

    int am = lane & 15;
    int k0 = (lane >> 4) * 8;

    for (int icc = 0; icc < 2; ++icc) {
        __syncthreads();
        for (int i = tid; i < 720; i += 256) {
            int pix = i >> 2, j8 = (i & 3) * 8;
            int hy = pix / 18, hx = pix % 18;
            int gy = ty0 + hy - 1, gx = tx0 + hx - 1;
            half8 vh = {}, vl = {};
            if (gy >= 0 && gy < S && gx >= 0 && gx < S) {
                size_t src = (((size_t)b * S + gy) * S + gx) * 64 + icc * 32 + j8;
                vh = *(const half8*)&in[src];
                vl = *(const half8*)&in[NEin + src];
            }
            *(half8*)&lds[pix * 40 + j8] = vh;
            *(half8*)&lds[7200 + pix * 40 + j8] = vl;
        }
        __syncthreads();

#pragma unroll
        for (int ky = 0; ky < 3; ++ky)
#pragma unroll
            for (int kx = 0; kx < 3; ++kx) {
                int tap = ky * 3 + kx;
                const _Float16* wp = wb + (tap * 2 + icc) * 2048 + lane * 8;
                half8 bhi[4], blo[4];
#pragma unroll
                for (int nt = 0; nt < 4; ++nt) {
                    bhi[nt] = *(const half8*)(wp + nt * 512);
                    blo[nt] = *(const half8*)(wp + nt * 512 + 36864);
                }
#pragma unroll
                for (int mt = 0; mt < 2; ++mt) {
                    int MT = wv * 2 + mt;
                    int Q = MT * 4 + (am >> 2), s = am & 3;
                    int py = (Q >> 3) * 2 + (s >> 1), px = (Q & 7) * 2 + (s & 1);
                    const _Float16* ap = &lds[((py + ky) * 18 + (px + kx)) * 40 + k0];
                    half8 ahi = *(const half8*)ap;
                    half8 alo = *(const half8*)(ap + 7200);
#pragma unroll
                    for (int nt = 0; nt < 4; ++nt) {
                        acc1[mt][nt] = __builtin_amdgcn_mfma_f32_16x16x32_f16(
                            ahi, bhi[nt], acc1[mt][nt], 0, 0, 0);
                        acc2[mt][nt] = __builtin_amdgcn_mfma_f32_16x16x32_f16(
                            ahi, blo[nt], acc2[mt][nt], 0, 0, 0);
                        acc2[mt][nt] = __builtin_amdgcn_mfma_f32_16x16x32_f16(
                            alo, bhi[nt], acc2[mt][nt], 0, 0, 0);
                    }
                }
            }
    }

    int cn = lane & 15, rq = lane >> 4;
#pragma unroll
    for (int mt = 0; mt < 2; ++mt) {
        int MT = wv * 2 + mt;
        int Q = MT * 4 + rq;
        int qy = Q >> 3, qx = Q & 7;
#pragma unroll
        for (int nt = 0; nt < 4; ++nt) {
            int oc = nt * 16 + cn;
            float vals[4];
#pragma unroll
            for (int r = 0; r < 4; ++r)
                vals[r] = acc1[mt][nt][r] + acc2[mt][nt][r] * LO_INV + bv[nt];
            if (POOL) {
                float m = fmaxf(fmaxf(vals[0], vals[1]), fmaxf(vals[2], vals[3]));
                m = fmaxf(m, 0.f);
                int opy = (ty0 >> 1) + qy, opx = (tx0 >> 1) + qx;
                size_t o = (((size_t)b * (S / 2) + opy) * (S / 2) + opx) * 64 + oc;
                _Float16 h = (_Float16)m;
                out[o] = h;
                out[NEout + o] = (_Float16)((m - (float)h) * LO_SCALE);
            } else {
#pragma unroll
                for (int r = 0; r < 4; ++r) {
                    int py = qy * 2 + (r >> 1), px = qx * 2 + (r & 1);
                    size_t o = (((size_t)b * S + (ty0 + py)) * S + (tx0 + px)) * 64 + oc;
                    float v = vals[r];
                    if (RES) v += (float)res[o] + (float)res[NEin + o] * LO_INV;
                    v = fmaxf(v, 0.f);
                    _Float16 h = (_Float16)v;
                    out[o] = h;
                    out[NEout + o] = (_Float16)((v - (float)h) * LO_SCALE);
                }
            }
        }
    }
}

// ---------------- proj (MFMA): per-sample GEMM C[256px][512oc], K=64.
__global__ __launch_bounds__(256)
void projm_k(const _Float16* __restrict__ in /* planes, NE2=4194304 */,
             const _Float16* __restrict__ pw, const float* __restrict__ bias,
             _Float16* __restrict__ outh /* hi plane; lo at +8388608 */) {
    const size_t NE2 = 4194304;
    int b = blockIdx.x;
    __shared__ float lt[64 * 65];
    int tid = threadIdx.x, lane = tid & 63, wv = tid >> 6;
    int row = lane & 15, cseg = lane >> 4;

    half8 ah[4][2], al[4][2];
#pragma unroll
    for (int mt = 0; mt < 4; ++mt) {
        int MT = wv * 4 + mt;
        int Q = MT * 4 + (row >> 2), s = row & 3;
        int y = (Q >> 3) * 2 + (s >> 1), x = (Q & 7) * 2 + (s & 1);
        size_t pb = ((size_t)b * 256 + y * 16 + x) * 64 + cseg * 8;
#pragma unroll
        for (int icc = 0; icc < 2; ++icc) {
            ah[mt][icc] = *(const half8*)&in[pb + icc * 32];
            al[mt][icc] = *(const half8*)&in[NE2 + pb + icc * 32];
        }
    }

    for (int ogl = 0; ogl < 4; ++ogl) {
        int og = blockIdx.y * 4 + ogl;
        half8 bh[4][2], bl[4][2];
#pragma unroll
        for (int ntl = 0; ntl < 4; ++ntl)
#pragma unroll
            for (int icc = 0; icc < 2; ++icc) {
                int nt = og * 4 + ntl;
                const _Float16* wp = pw + ((nt * 2 + icc) * 64 + lane) * 8;
                bh[ntl][icc] = *(const half8*)wp;
                bl[ntl][icc] = *(const half8*)(wp + 32768);
            }
        f32x4 a1[4][4] = {};
        f32x4 a2[4][4] = {};
#pragma unroll
        for (int icc = 0; icc < 2; ++icc)
#pragma unroll
            for (int mt = 0; mt < 4; ++mt)
#pragma unroll
                for (int ntl = 0; ntl < 4; ++ntl) {
                    a1[mt][ntl] = __builtin_amdgcn_mfma_f32_16x16x32_f16(
                        ah[mt][icc], bh[ntl][icc], a1[mt][ntl], 0, 0, 0);
                    a2[mt][ntl] = __builtin_amdgcn_mfma_f32_16x16x32_f16(
                        ah[mt][icc], bl[ntl][icc], a2[mt][ntl], 0, 0, 0);
                    a2[mt][ntl] = __builtin_amdgcn_mfma_f32_16x16x32_f16(
                        al[mt][icc], bh[ntl][icc], a2[mt][ntl], 0, 0, 0);
                }
        if (ogl) __syncthreads();
#pragma unroll
        for (int mt = 0; mt < 4; ++mt) {
            int Qg = (wv * 4 + mt) * 4 + (lane >> 4);
#pragma unroll
            for (int ntl = 0; ntl < 4; ++ntl) {
                float bvv = bias[og * 64 + ntl * 16 + (lane & 15)];
                float v0 = a1[mt][ntl][0] + a2[mt][ntl][0] * LO_INV + bvv;
                float v1 = a1[mt][ntl][1] + a2[mt][ntl][1] * LO_INV + bvv;
                float v2 = a1[mt][ntl][2] + a2[mt][ntl][2] * LO_INV + bvv;
                float v3 = a1[mt][ntl][3] + a2[mt][ntl][3] * LO_INV + bvv;
                float m = fmaxf(fmaxf(fmaxf(v0, v1), fmaxf(v2, v3)), 0.f);
                lt[(ntl * 16 + (lane & 15)) * 65 + Qg] = m;
            }
        }
        __syncthreads();
#pragma unroll
        for (int r = 0; r < 16; ++r) {
            int f = r * 256 + tid;
            int ol = f >> 6, q = f & 63;
            float v = lt[ol * 65 + q];
            _Float16 h = (_Float16)v;
            _Float16 l = (_Float16)((v - (float)h) * LO_SCALE);
            size_t o = (size_t)b * 32768 + og * 4096 + ol * 64 + q;
            outh[o] = h;
            outh[8388608 + o] = l;
        }
    }
}

// ---------------- fc1 MFMA GEMM: C[256][1024] = A[256][32768] @ W[1024][32768]^T
// Double-buffered LDS stride 40, one barrier per K-step. A = f16 planes
// (pure-copy staging), W converted in-kernel. Split-K 32, grid 512.
__global__ __launch_bounds__(256)
void fc1m_k(const _Float16* __restrict__ Ahl /* hi; lo at +8388608 */,
            const float* __restrict__ W,
            float* __restrict__ partial /* [32][256][1024] */) {
    int bid = blockIdx.x;
    int lid = (bid & 7) * 64 + (bid >> 3);   // bijective, 512 = 8*64
    int mt = lid & 1, nt = (lid >> 1) & 7, ks = lid >> 4;  // ks 0..31
    int m0 = mt * 128, n0 = nt * 128;
    const _Float16* Ab = Ahl + (size_t)m0 * 32768 + ks * 1024;
    const float* Wb = W + (size_t)n0 * 32768 + ks * 1024;

    __shared__ __align__(16) _Float16 lds[40960];  // 2 buffers x 20480

    int tid = threadIdx.x, lane = tid & 63, wv = tid >> 6;
    int wm = (wv & 1) * 64, wn = (wv >> 1) * 64;
    int koff = (lane >> 4) * 8, fr = lane & 15;

    f32x4 acc1[4][4] = {};
    f32x4 acc2[4][4] = {};

    int arow[2], ak8[2];
#pragma unroll
    for (int p = 0; p < 2; ++p) {
        int idx = p * 256 + tid;
        arow[p] = idx >> 2;
        ak8[p] = (idx & 3) * 8;
    }
    int wrow[4], wc4[4];
#pragma unroll
    for (int p = 0; p < 4; ++p) {
        int idx = p * 256 + tid;
        wrow[p] = idx >> 3;
        wc4[p] = (idx & 7) << 2;
    }

    half8 pa_h[2], pa_l[2];
    float4 rw[4];

#pragma unroll
    for (int p = 0; p < 2; ++p) {
        pa_h[p] = *(const half8*)&Ab[(size_t)arow[p] * 32768 + ak8[p]];
        pa_l[p] = *(const half8*)&Ab[8388608 + (size_t)arow[p] * 32768 + ak8[p]];
    }
#pragma unroll
    for (int p = 0; p < 4; ++p)
        rw[p] = *(const float4*)&Wb[(size_t)wrow[p] * 32768 + wc4[p]];
    {
        _Float16* b0p = lds;
#pragma unroll
        for (int p = 0; p < 2; ++p) {
            *(half8*)&b0p[arow[p] * 40 + ak8[p]] = pa_h[p];
            *(half8*)&b0p[5120 + arow[p] * 40 + ak8[p]] = pa_l[p];
        }
#pragma unroll
        for (int p = 0; p < 4; ++p) {
            float4 u = rw[p];
            _Float16 g0 = (_Float16)u.x, g1 = (_Float16)u.y;
            _Float16 g2 = (_Float16)u.z, g3 = (_Float16)u.w;
            half4_t gh = {g0, g1, g2, g3};
            half4_t gl = {(_Float16)((u.x - (float)g0) * LO_SCALE),
                          (_Float16)((u.y - (float)g1) * LO_SCALE),
                          (_Float16)((u.z - (float)g2) * LO_SCALE),
                          (_Float16)((u.w - (float)g3) * LO_SCALE)};
            *(half4_t*)&b0p[10240 + wrow[p] * 40 + wc4[p]] = gh;
            *(half4_t*)&b0p[15360 + wrow[p] * 40 + wc4[p]] = gl;
        }
    }
#pragma unroll
    for (int p = 0; p < 2; ++p) {
        pa_h[p] = *(const half8*)&Ab[(size_t)arow[p] * 32768 + 32 + ak8[p]];
        pa_l[p] = *(const half8*)&Ab[8388608 + (size_t)arow[p] * 32768 + 32 + ak8[p]];
    }
#pragma unroll
    for (int p = 0; p < 4; ++p)
        rw[p] = *(const float4*)&Wb[(size_t)wrow[p] * 32768 + 32 + wc4[p]];
    __syncthreads();

    for (int kt = 0; kt < 32; ++kt) {
        _Float16* cur = lds + (kt & 1) * 20480;
        _Float16* nxt = lds + ((kt + 1) & 1) * 20480;
        if (kt < 31) {
#pragma unroll
            for (int p = 0; p < 2; ++p) {
                *(half8*)&nxt[arow[p] * 40 + ak8[p]] = pa_h[p];
                *(half8*)&nxt[5120 + arow[p] * 40 + ak8[p]] = pa_l[p];
            }
#pragma unroll
            for (int p = 0; p < 4; ++p) {
                float4 u = rw[p];
                _Float16 g0 = (_Float16)u.x, g1 = (_Float16)u.y;
                _Float16 g2 = (_Float16)u.z, g3 = (_Float16)u.w;
                half4_t gh = {g0, g1, g2, g3};
                half4_t gl = {(_Float16)((u.x - (float)g0) * LO_SCALE),
                              (_Float16)((u.y - (float)g1) * LO_SCALE),
                              (_Float16)((u.z - (float)g2) * LO_SCALE),
                              (_Float16)((u.w - (float)g3) * LO_SCALE)};
                *(half4_t*)&nxt[10240 + wrow[p] * 40 + wc4[p]] = gh;
                *(half4_t*)&nxt[15360 + wrow[p] * 40 + wc4[p]] = gl;
            }
            if (kt < 30) {
                int kb = (kt + 2) * 32;
#pragma unroll
                for (int p = 0; p < 2; ++p) {
                    pa_h[p] = *(const half8*)&Ab[(size_t)arow[p] * 32768 + kb + ak8[p]];
                    pa_l[p] = *(const half8*)&Ab[8388608 + (size_t)arow[p] * 32768 + kb + ak8[p]];
                }
#pragma unroll
                for (int p = 0; p < 4; ++p)
                    rw[p] = *(const float4*)&Wb[(size_t)wrow[p] * 32768 + kb + wc4[p]];
            }
        }
        half8 bh[4], bl[4];
#pragma unroll
        for (int nf = 0; nf < 4; ++nf) {
            int r = wn + nf * 16 + fr;
            bh[nf] = *(const half8*)&cur[10240 + r * 40 + koff];
            bl[nf] = *(const half8*)&cur[15360 + r * 40 + koff];
        }
#pragma unroll
        for (int mf = 0; mf < 4; ++mf) {
            int r = wm + mf * 16 + fr;
            half8 ah = *(const half8*)&cur[r * 40 + koff];
            half8 al = *(const half8*)&cur[5120 + r * 40 + koff];
#pragma unroll
            for (int nf = 0; nf < 4; ++nf) {
                acc1[mf][nf] = __builtin_amdgcn_mfma_f32_16x16x32_f16(
                    ah, bh[nf], acc1[mf][nf], 0, 0, 0);
                acc2[mf][nf] = __builtin_amdgcn_mfma_f32_16x16x32_f16(
                    ah, bl[nf], acc2[mf][nf], 0, 0, 0);
                acc2[mf][nf] = __builtin_amdgcn_mfma_f32_16x16x32_f16(
                    al, bh[nf], acc2[mf][nf], 0, 0, 0);
            }
        }
        __syncthreads();
    }

    int rq = lane >> 4, cn = lane & 15;
    float* pb = partial + (size_t)ks * 262144;
#pragma unroll
    for (int mf = 0; mf < 4; ++mf)
#pragma unroll
        for (int nf = 0; nf < 4; ++nf) {
            int n = n0 + wn + nf * 16 + cn;
#pragma unroll
            for (int r = 0; r < 4; ++r) {
                int m = m0 + wm + mf * 16 + rq * 4 + r;
                pb[(size_t)m * 1024 + n] = acc1[mf][nf][r] + acc2[mf][nf][r] * LO_INV;
            }
        }
}

__global__ __launch_bounds__(256)
void fc1red_k(const float* __restrict__ partial, const float* __restrict__ b1,
              float* __restrict__ fc1o_t /* [n][m] */) {
    int m = blockIdx.x;
    int n0 = threadIdx.x * 4;
    float4 s = {0.f, 0.f, 0.f, 0.f};
    for (int ks = 0; ks < 32; ++ks) {
        float4 v = *(const float4*)&partial[((size_t)ks * 256 + m) * 1024 + n0];
        s.x += v.x; s.y += v.y; s.z += v.z; s.w += v.w;
    }
    fc1o_t[(size_t)(n0 + 0) * 256 + m] = fmaxf(s.x + b1[n0 + 0], 0.f);
    fc1o_t[(size_t)(n0 + 1) * 256 + m] = fmaxf(s.y + b1[n0 + 1], 0.f);
    fc1o_t[(size_t)(n0 + 2) * 256 + m] = fmaxf(s.z + b1[n0 + 2], 0.f);
    fc1o_t[(size_t)(n0 + 3) * 256 + m] = fmaxf(s.w + b1[n0 + 3], 0.f);
}

__global__ __launch_bounds__(256)
void fc2a_k(const float* __restrict__ a_t, const float* __restrict__ W2,
            float* __restrict__ p2) {
    int n2 = blockIdx.x, ks = blockIdx.y;
    int m = threadIdx.x;
    float acc = 0.f;
    for (int k = ks * 256; k < ks * 256 + 256; ++k)
        acc = fmaf(a_t[(size_t)k * 256 + m], W2[n2 * 1024 + k], acc);
    p2[((size_t)n2 * 4 + ks) * 256 + m] = acc;
}

__global__ __launch_bounds__(512)
void fc2b_k(const float* __restrict__ p2, const float* __restrict__ b2,
            float* __restrict__ out) {
    int i = threadIdx.x;
    int m = i >> 1, n2 = i & 1;
    float s = b2[n2];
#pragma unroll
    for (int ks = 0; ks < 4; ++ks) s += p2[((size_t)n2 * 4 + ks) * 256 + m];
    out[m * 2 + n2] = s;
}

// ---------------------------------------------------------------------------
extern "C" void kernel_launch(void* const* d_in, const int* in_sizes, int n_in,
                              void* d_out, int out_size, void* d_ws, size_t ws_size,
                              hipStream_t stream) {
    const float* image   = (const float*)d_in[0];
    const int*   question= (const int*)d_in[1];
    const float* stem_w0 = (const float*)d_in[2];
    const float* stem_b0 = (const float*)d_in[3];
    const float* stem_w  = (const float*)d_in[4];
    const float* stem_b  = (const float*)d_in[5];
    const float* exp_w1  = (const float*)d_in[6];
    const float* exp_b1  = (const float*)d_in[7];
    const float* exp_w2  = (const float*)d_in[8];
    const float* exp_b2  = (const float*)d_in[9];
    const float* proj_w  = (const float*)d_in[10];
    const float* proj_b  = (const float*)d_in[11];
    const float* fc1_w   = (const float*)d_in[12];
    const float* fc1_b   = (const float*)d_in[13];
    const float* fc2_w   = (const float*)d_in[14];
    const float* fc2_b   = (const float*)d_in[15];
    (void)in_sizes; (void)n_in; (void)out_size; (void)ws_size;

    float* ws = (float*)d_ws;
    const size_t A = 16777216, P2N = 4194304;
    float* wtr   = ws + 2 * A + P2N;
    _Float16* c1wF = (_Float16*)wtr;            // 4096 f16 = 2048 floats
    _Float16* pwF = (_Float16*)(wtr + 2048);    // 65536 f16 = 32768 floats
    float* pfc2  = wtr + 2048 + 32768;          // 2048 fp32
    _Float16* f16b = (_Float16*)(wtr + 36864);
    _Float16* stemtF = f16b;                    // 3 layers * 73728 f16
    _Float16* e1tF   = f16b + 3 * 73728;        // 16 layers
    _Float16* e2tF   = e1tF + 16 * 73728;       // 16 layers
    _Float16* p1h  = (_Float16*)ws;
    _Float16* h2h  = (_Float16*)(ws + A);
    _Float16* p2h  = (_Float16*)(ws + 2 * A);
    _Float16* hAh  = (_Float16*)ws;             // p1 dead by then
    _Float16* hBh  = (_Float16*)(ws + P2N);
    _Float16* hCh  = (_Float16*)(ws + 2 * P2N);
    _Float16* pool3h = (_Float16*)(ws + A);     // h2 dead by then
    float* fc1o  = ws + A + 8388608;
    float* fc1p  = ws;                          // [32][256][1024]

    // fused weight transforms (1325056 ids = 5176 blocks)
    allwx_k<<<5176, 256, 0, stream>>>(stem_w0, proj_w, stem_w, exp_w1, exp_w2,
                                      c1wF, pwF, stemtF, e1tF, e2tF);

    // stem
    conv1m_k<<<dim3(256, 32), 256, 0, stream>>>(image, c1wF, stem_b0, p1h);
    convm_k<32, false, false><<<dim3(256, 8), 256, 0, stream>>>(
        p1h, h2h, stemtF, stem_b, nullptr, nullptr, 0);
    convm_k<32, true, false><<<dim3(256, 8), 256, 0, stream>>>(
        h2h, p2h, stemtF + 73728, stem_b + 64, nullptr, nullptr, 0);
    convm_k<16, false, false><<<dim3(256, 2), 256, 0, stream>>>(
        p2h, hAh, stemtF + 2 * 73728, stem_b + 128, nullptr, nullptr, 0);

    // expert residual rounds (cols 4,5,7)
    const int cols[3] = {4, 5, 7};
    _Float16* hin = hAh;
    _Float16* hmid = hBh;
    _Float16* hout = hCh;
    for (int r = 0; r < 3; ++r) {
        convm_k<16, false, false><<<dim3(256, 2), 256, 0, stream>>>(
            hin, hmid, e1tF, exp_b1, nullptr, question, cols[r]);
        convm_k<16, false, true><<<dim3(256, 2), 256, 0, stream>>>(
            hmid, hout, e2tF, exp_b2, hin, question, cols[r]);
        _Float16* tp = hin; hin = hout; hout = hmid; hmid = tp;
    }
    // hin == final h (ws+0)

    // head
    projm_k<<<dim3(256, 2), 256, 0, stream>>>(hin, pwF, proj_b, pool3h);
    fc1m_k<<<512, 256, 0, stream>>>(pool3h, fc1_w, fc1p);
    fc1red_k<<<256, 256, 0, stream>>>(fc1p, fc1_b, fc1o);
    fc2a_k<<<dim3(2, 4), 256, 0, stream>>>(fc1o, fc2_w, pfc2);
    fc2b_k<<<1, 512, 0, stream>>>(pfc2, fc2_b, (float*)d_out);
}